// Round 9
// baseline (361.658 us; speedup 1.0000x reference)
//
#include <hip/hip_runtime.h>
#include <hip/hip_bf16.h>

// SNNDecode: z = x @ W^T  (einsum 'bsh,oh->sbo'), then linear LI scan over seq.
//   v_t = v_{t-1} + a*(i_{t-1} - v_{t-1});  i_t = (1-b)*i_{t-1} + z_t;  out[t]=v_t
// d_out = [voltages (2048*64*128)] ++ [v_f (8192)] ++ [i_f (8192)]  (fp32)
//
// Round 9: round-8 single-pass design, but with a MANUAL grid barrier instead
// of hipLaunchCooperativeKernel (which silently failed to launch in round 8:
// all-zero output). Residency argument: static LDS ~69.2 KB -> 2 blocks/CU
// (138.4 <= 160 KB), launch_bounds(256,2) -> VGPR <= 256 -> 8 waves/CU fit;
// grid 512 = 256 CU x 2, so ALL blocks are co-resident by capacity and the
// release/acquire device-scope barrier (rocPRIM decoupled-lookback pattern,
// __threadfence for cross-XCD L2) cannot deadlock.
// Block (r,k): tiles jt=2k,2k+1 of batch row r. Pre-barrier: gemm + in-LDS
// local scan both tiles (A flushed uncorrected, B kept in LDS), publish tile
// end-states. Barrier. Post: prefix-combine, correct B in LDS + single write,
// RMW own A tile (L2-hot), k==7 writes finals.
// ws: [0,512K) vT[16][8192] | [512K,1M) iT | [1M,+128K) bf16 W | ctr @1M+128K.

typedef __attribute__((ext_vector_type(4))) float    f4;
typedef __attribute__((ext_vector_type(8))) short    s8;
typedef __attribute__((ext_vector_type(4))) unsigned u4;

#define SEQ    2048
#define HID    512
#define CHAINS 8192          // batch(64) * out(128)
#define VOLT   16777216      // SEQ * CHAINS
#define NT     16            // 128-step tiles per batch row
#define NBLK   512

__device__ __forceinline__ float clamp01(float x) { return fminf(fmaxf(x, 0.f), 1.f); }

__device__ __forceinline__ unsigned pkbf(float x, float y) {
  float2 t; t.x = x; t.y = y;
  union { __hip_bfloat162 h; unsigned u; } c;
  c.h = __float22bfloat162_rn(t);
  return c.u;
}

__device__ __forceinline__ short f2bf(float f) {
  union { float f; unsigned u; } c; c.f = f;
  unsigned u = c.u;
  unsigned r = (u + 0x7fffu + ((u >> 16) & 1u)) >> 16;
  return (short)r;
}

// LDS swizzle (ushort-index units): conflict-free for both ds_write_b128
// staging and ds_read_b128 fragment reads (round-1-verified).
__device__ __forceinline__ int swz(int row, int k) {
  return (row * 64 + k) ^ ((row & 7) << 3);
}

// ---------------- Phase 0: W (fp32 [128][512]) -> bf16 in ws ---------------
__global__ __launch_bounds__(256) void k_wconv(const float* __restrict__ W,
                                               unsigned short* __restrict__ Wb) {
  const int i = blockIdx.x * 256 + threadIdx.x;
  const f4 lo = ((const f4*)W)[2 * i];
  const f4 hi = ((const f4*)W)[2 * i + 1];
  s8 v;
#pragma unroll
  for (int j = 0; j < 4; ++j) { v[j] = f2bf(lo[j]); v[j + 4] = f2bf(hi[j]); }
  ((s8*)Wb)[i] = v;
}

// ---------------- The single-pass everything-kernel ------------------------
__global__ __launch_bounds__(256, 2) void k_main(const float* __restrict__ X,
                                                 const unsigned short* __restrict__ Wb,
                                                 float* __restrict__ Out,
                                                 const float* __restrict__ tau_syn,
                                                 const float* __restrict__ tau_mem,
                                                 float* __restrict__ ws,
                                                 unsigned* __restrict__ ctr) {
  __shared__ __align__(16) char smem[65536];
  __shared__ __align__(16) float tAs[128], tBs[128];   // alpha_{j+1}, beta_{j+1}
  __shared__ __align__(16) float vh[2][128], ih[2][128];
  __shared__ __align__(16) float inV[2][128], inI[2][128];
  __shared__ float sc[2];                              // eb^64, eb^128
  short* const AS = (short*)smem;            // [2][128][64] bf16 A tiles
  float* const ZS = (float*)smem;            // [128][128] f32 z/v tile (alias)

  const int tid = threadIdx.x;
  const int blk = blockIdx.x;
  const int r   = blk >> 3;          // batch row 0..63
  const int k   = blk & 7;           // tile-pair 0..7

  const float a  = 0.001f * clamp01(tau_mem[0]);
  const float bb = 0.001f * clamp01(tau_syn[0]);
  const float ea = 1.f - a, eb = 1.f - bb;

  if (tid == 0) {   // alpha/beta tables (verified recurrence, round 7)
    float al = 1.f, be = 0.f, ep = 1.f;
    for (int j = 0; j < 128; ++j) {
      const float aln = al * ea;
      be = al * a + be * eb;
      al = aln;
      ep *= eb;
      tAs[j] = al; tBs[j] = be;
      if (j == 63) sc[0] = ep;
    }
    sc[1] = ep;
  }

  const int rbase = tid >> 3;
  const int coff  = (tid & 7) << 3;
  const int lane  = tid & 63;
  const int wid   = tid >> 6;
  const int wmb   = (wid >> 1) << 6;
  const int wnb   = (wid & 1) << 6;
  const int lr    = lane & 15;
  const int lk    = (lane >> 4) << 3;

  const unsigned short* pB[4];
#pragma unroll
  for (int ni = 0; ni < 4; ++ni)
    pB[ni] = Wb + (size_t)(wnb + (ni << 4) + lr) * HID + lk;

  for (int tile = 0; tile < 2; ++tile) {
    const int jt = (k << 1) + tile;
    const int m0 = (r << 11) + (jt << 7);
    __syncthreads();   // tables ready (tile0) / previous tile's LDS readers done

    const float* pX[4];
#pragma unroll
    for (int c = 0; c < 4; ++c)
      pX[c] = X + (size_t)(m0 + (c << 5) + rbase) * HID + coff;

    f4 acc[4][4];
#pragma unroll
    for (int mi = 0; mi < 4; ++mi)
#pragma unroll
      for (int ni = 0; ni < 4; ++ni) acc[mi][ni] = (f4){0.f, 0.f, 0.f, 0.f};

    f4 xa[3][4][2];
#pragma unroll
    for (int c = 0; c < 4; ++c) {
      xa[0][c][0] = *(const f4*)(pX[c]);
      xa[0][c][1] = *(const f4*)(pX[c] + 4);
      xa[1][c][0] = *(const f4*)(pX[c] + 64);
      xa[1][c][1] = *(const f4*)(pX[c] + 68);
    }

#pragma unroll
    for (int ks = 0; ks < 8; ++ks) {
      const int cur = ks % 3;
      short* const Ac = AS + ((ks & 1) << 13);
#pragma unroll
      for (int c = 0; c < 4; ++c) {
        const int row = (c << 5) + rbase;
        u4 va;
        va[0] = pkbf(xa[cur][c][0][0], xa[cur][c][0][1]);
        va[1] = pkbf(xa[cur][c][0][2], xa[cur][c][0][3]);
        va[2] = pkbf(xa[cur][c][1][0], xa[cur][c][1][1]);
        va[3] = pkbf(xa[cur][c][1][2], xa[cur][c][1][3]);
        *(u4*)&Ac[swz(row, coff)] = va;
      }
      __syncthreads();
      s8 bg[2][4];
#pragma unroll
      for (int kk = 0; kk < 2; ++kk)
#pragma unroll
        for (int ni = 0; ni < 4; ++ni)
          bg[kk][ni] = *(const s8*)(pB[ni] + (ks << 6) + (kk << 5));
      if (ks < 6) {
        const int k0 = (ks + 2) << 6;
        const int nxt = (ks + 2) % 3;
#pragma unroll
        for (int c = 0; c < 4; ++c) {
          xa[nxt][c][0] = *(const f4*)(pX[c] + k0);
          xa[nxt][c][1] = *(const f4*)(pX[c] + k0 + 4);
        }
      }
#pragma unroll
      for (int kk = 0; kk < 2; ++kk) {
        s8 af[4];
#pragma unroll
        for (int mi = 0; mi < 4; ++mi)
          af[mi] = *(const s8*)&Ac[swz(wmb + (mi << 4) + lr, (kk << 5) + lk)];
#pragma unroll
        for (int mi = 0; mi < 4; ++mi)
#pragma unroll
          for (int ni = 0; ni < 4; ++ni)
            acc[mi][ni] = __builtin_amdgcn_mfma_f32_16x16x32_bf16(af[mi], bg[kk][ni],
                                                                  acc[mi][ni], 0, 0, 0);
      }
    }

    // park z tile in LDS (aliases AS; all waves done reading AS after sync)
    __syncthreads();
    const int rr = (lane >> 4) << 2;
#pragma unroll
    for (int mi = 0; mi < 4; ++mi)
#pragma unroll
      for (int ni = 0; ni < 4; ++ni)
#pragma unroll
        for (int rg = 0; rg < 4; ++rg)
          ZS[(wmb + (mi << 4) + rr + rg) * 128 + wnb + (ni << 4) + lr] = acc[mi][ni][rg];
    __syncthreads();

    // parallel half-scans from zero state (v overwrites z in place)
    {
      const int h = tid >> 7, col = tid & 127;
      float* zc = ZS + ((h << 6) * 128) + col;
      float v = 0.f, ii = 0.f;
#pragma unroll 8
      for (int j = 0; j < 64; ++j) {
        const float z = zc[j * 128];
        v  = v + a * (ii - v);
        zc[j * 128] = v;
        ii = eb * ii + z;
      }
      vh[h][col] = v; ih[h][col] = ii;
    }
    __syncthreads();
    // table-driven parallel splice of half 1 (rank-2 in half-0 end state)
    {
      const int col = tid & 127, jh = tid >> 7;
      const float v0 = vh[0][col], i0 = ih[0][col];
      float* zc1 = ZS + (64 + (jh << 5)) * 128 + col;
#pragma unroll 8
      for (int jj = 0; jj < 32; ++jj) {
        const int j = (jh << 5) + jj;
        zc1[jj * 128] += tAs[j] * v0 + tBs[j] * i0;
      }
    }
    // publish tile end-state (reads vh/ih + tables; stable since last sync)
    if (tid < 128) {
      const int col = tid;
      const float vE = vh[1][col] + tAs[63] * vh[0][col] + tBs[63] * ih[0][col];
      const float iE = ih[1][col] + sc[0] * ih[0][col];
      ws[(size_t)jt * CHAINS + (r << 7) + col]        = vE;
      ws[(size_t)(NT + jt) * CHAINS + (r << 7) + col] = iE;
    }
    if (tile == 0) {   // uniform branch: flush A's v_local (uncorrected) to Out
      __syncthreads();
      float* const Orow = Out + (size_t)(jt << 7) * 8192 + (r << 7);
#pragma unroll
      for (int i = 0; i < 16; ++i) {
        const int idx  = (i << 8) + tid;
        const int toff = idx >> 5;
        const int c4   = idx & 31;
        *(f4*)(Orow + (size_t)toff * 8192 + (c4 << 2)) = *(const f4*)&ZS[toff * 128 + (c4 << 2)];
      }
    }
  }

  // -------- manual grid barrier (all 512 blocks co-resident by capacity) ---
  __threadfence();           // device-scope: publish ws/Out across XCD L2s
  __syncthreads();
  if (tid == 0) {
    __hip_atomic_fetch_add(ctr, 1u, __ATOMIC_RELEASE, __HIP_MEMORY_SCOPE_AGENT);
    while (__hip_atomic_load(ctr, __ATOMIC_ACQUIRE, __HIP_MEMORY_SCOPE_AGENT) < NBLK)
      __builtin_amdgcn_s_sleep(8);
  }
  __syncthreads();
  __threadfence();           // acquire side: invalidate stale lines

  // -------- combine: prefix over earlier tiles (independent loads) ---------
  const int jtA = k << 1, jtB = jtA + 1;
  const float P = tAs[127], Q = tBs[127], R = sc[1];
  if (tid < 128) {
    const int col = tid, chain = (r << 7) + col;
    float sv = 0.f, si = 0.f;
    for (int p = 0; p < jtA; ++p) {
      const float ve = ws[(size_t)p * CHAINS + chain];
      const float ie = ws[(size_t)(NT + p) * CHAINS + chain];
      const float nv = P * sv + Q * si + ve;
      si = R * si + ie;
      sv = nv;
    }
    inV[0][col] = sv; inI[0][col] = si;                 // in-state of tile A
    const float eAv = ws[(size_t)jtA * CHAINS + chain];
    const float eAi = ws[(size_t)(NT + jtA) * CHAINS + chain];
    const float bv2 = P * sv + Q * si + eAv;            // in-state of tile B
    const float bi2 = R * si + eAi;
    inV[1][col] = bv2; inI[1][col] = bi2;
    if (k == 7) {                                       // finals after tile 15
      const float eBv = ws[(size_t)jtB * CHAINS + chain];
      const float eBi = ws[(size_t)(NT + jtB) * CHAINS + chain];
      Out[VOLT + chain]          = P * bv2 + Q * bi2 + eBv;   // v_f
      Out[VOLT + CHAINS + chain] = R * bi2 + eBi;             // i_f
    }
  }
  __syncthreads();

  // -------- correct tile B in LDS (rank-2, table-driven, parallel) ---------
  {
    const int col = tid & 127, jh = tid >> 7;
    const float bv = inV[1][col], bi = inI[1][col];
    float* zc = ZS + ((jh << 6) * 128) + col;
#pragma unroll 8
    for (int jj = 0; jj < 64; ++jj) {
      const int j = (jh << 6) + jj;
      zc[jj * 128] += tAs[j] * bv + tBs[j] * bi;
    }
  }
  __syncthreads();

  // -------- write tile B (single, final) -----------------------------------
  {
    float* const OrowB = Out + (size_t)(jtB << 7) * 8192 + (r << 7);
#pragma unroll
    for (int i = 0; i < 16; ++i) {
      const int idx  = (i << 8) + tid;
      const int toff = idx >> 5;
      const int c4   = idx & 31;
      *(f4*)(OrowB + (size_t)toff * 8192 + (c4 << 2)) = *(const f4*)&ZS[toff * 128 + (c4 << 2)];
    }
  }
  // -------- RMW own tile A (L2-hot: this block wrote it) -------------------
  {
    float* const OrowA = Out + (size_t)(jtA << 7) * 8192 + (r << 7);
#pragma unroll
    for (int i = 0; i < 16; ++i) {
      const int idx  = (i << 8) + tid;
      const int toff = idx >> 5;
      const int c4   = idx & 31;
      f4* p = (f4*)(OrowA + (size_t)toff * 8192 + (c4 << 2));
      const f4 vv = *(const f4*)&inV[0][c4 << 2];
      const f4 iv = *(const f4*)&inI[0][c4 << 2];
      *p = *p + tAs[toff] * vv + tBs[toff] * iv;
    }
  }
}

extern "C" void kernel_launch(void* const* d_in, const int* in_sizes, int n_in,
                              void* d_out, int out_size, void* d_ws, size_t ws_size,
                              hipStream_t stream) {
  const float* X   = (const float*)d_in[0];  // [64][2048][512]
  const float* W   = (const float*)d_in[1];  // [128][512]
  const float* tsy = (const float*)d_in[2];
  const float* tme = (const float*)d_in[3];
  float* Out = (float*)d_out;
  float* ws  = (float*)d_ws;                 // 1 MiB states + 128 KiB Wb + ctr
  unsigned short* Wb = (unsigned short*)((char*)d_ws + (1u << 20));
  unsigned* ctr = (unsigned*)((char*)d_ws + (1u << 20) + (128u << 10));

  hipMemsetAsync(ctr, 0, 4, stream);         // reset barrier counter each call
  k_wconv<<<32, 256, 0, stream>>>(W, Wb);
  k_main<<<NBLK, 256, 0, stream>>>(X, Wb, Out, tsy, tme, ws, ctr);
}

// Round 10
// 104.216 us; speedup vs baseline: 3.4703x; 3.4703x over previous
//
#include <hip/hip_runtime.h>
#include <hip/hip_bf16.h>

// SNNDecode: z = x @ W^T  (einsum 'bsh,oh->sbo'), then linear LI scan over seq.
//   v_t = v_{t-1} + a*(i_{t-1} - v_{t-1});  i_t = (1-b)*i_{t-1} + z_t;  out[t]=v_t
// d_out = [voltages (2048*64*128)] ++ [v_f (8192)] ++ [i_f (8192)]  (fp32)
//
// Round 10: revert to the round-6 champion structure (3 kernels; measured
// 104.6-104.8 us), plus ONE change: z is stored as bf16 in ws (32 MB) instead
// of f32 in Out (64 MB), halving the z round-trip (-64 MB HBM). Emit's chunk
// in-states stay f32-accurate (prefix of f32 end-states), so bf16-z only
// perturbs a <=32-step local scan (~0.007 abs). Host guards on ws_size and
// falls back to the exact round-6 path if ws is too small.
// ws: [0,2M) vend[64][8192] | [2M,4M) iend | [4M,+128K) bf16 W |
//     [4M+128K, +32M) z bf16 [2048][8192]   (big-ws path only)

typedef __attribute__((ext_vector_type(4))) float          f4;
typedef __attribute__((ext_vector_type(8))) short          s8;
typedef __attribute__((ext_vector_type(4))) unsigned       u4;
typedef __attribute__((ext_vector_type(2))) unsigned       u2;
typedef __attribute__((ext_vector_type(4))) unsigned short su4;

#define SEQ    2048
#define HID    512
#define CHAINS 8192          // batch(64) * out(128)
#define VOLT   16777216      // SEQ * CHAINS
#define NCH    64            // SEQ / 32
#define CHUNK  32

__device__ __forceinline__ float clamp01(float x) { return fminf(fmaxf(x, 0.f), 1.f); }

// packed fp32x2 -> bf16x2 (RNE) as one u32; compiler emits v_cvt_pk_bf16_f32
__device__ __forceinline__ unsigned pkbf(float x, float y) {
  float2 t; t.x = x; t.y = y;
  union { __hip_bfloat162 h; unsigned u; } c;
  c.h = __float22bfloat162_rn(t);
  return c.u;
}

__device__ __forceinline__ short f2bf(float f) {
  union { float f; unsigned u; } c; c.f = f;
  unsigned u = c.u;
  unsigned r = (u + 0x7fffu + ((u >> 16) & 1u)) >> 16;
  return (short)r;
}

__device__ __forceinline__ float bf2f(unsigned short s) {
  union { unsigned u; float f; } c; c.u = ((unsigned)s) << 16; return c.f;
}

// LDS swizzle (ushort-index units): conflict-free for both ds_write_b128
// staging and ds_read_b128 fragment reads (round-1-verified).
__device__ __forceinline__ int swz(int row, int k) {
  return (row * 64 + k) ^ ((row & 7) << 3);
}

// ---------------- Phase 0: W (fp32 [128][512]) -> bf16 in ws ---------------
__global__ __launch_bounds__(256) void k_wconv(const float* __restrict__ W,
                                               unsigned short* __restrict__ Wb) {
  const int i = blockIdx.x * 256 + threadIdx.x;
  const f4 lo = ((const f4*)W)[2 * i];
  const f4 hi = ((const f4*)W)[2 * i + 1];
  s8 v;
#pragma unroll
  for (int j = 0; j < 4; ++j) { v[j] = f2bf(lo[j]); v[j + 4] = f2bf(hi[j]); }
  ((s8*)Wb)[i] = v;
}

// ---------------- Phase 1 (+2a): GEMM tile + z store + fused chunk scans ---
// ZB=1: z stored bf16 in zbf.  ZB=0: z stored f32 in Out (round-6 fallback).
template <int ZB>
__global__ __launch_bounds__(256, 2) void k_gemm(const float* __restrict__ X,
                                                 const unsigned short* __restrict__ Wb,
                                                 float* __restrict__ Out,
                                                 unsigned short* __restrict__ zbf,
                                                 const float* __restrict__ tau_syn,
                                                 const float* __restrict__ tau_mem,
                                                 float* __restrict__ ws) {
  __shared__ __align__(16) char smem[65536];
  short* const AS = (short*)smem;            // [2][128][64] bf16 A tiles (32 KB)
  float* const ZS = (float*)smem;            // [128][128] f32 z tile (aliased)

  const int tid = threadIdx.x;
  const int blk = blockIdx.x;
  const int m0  = blk << 7;          // global row = b*2048 + t
  const int bI  = blk >> 4;          // batch index
  const int t0  = (blk & 15) << 7;   // t tile base

  const int rbase = tid >> 3;        // 0..31: staging row group
  const int coff  = (tid & 7) << 3;  // staging k offset (8 elems)

  const int lane = tid & 63;
  const int wid  = tid >> 6;
  const int wmb  = (wid >> 1) << 6;  // wave row base: 0/64
  const int wnb  = (wid & 1) << 6;   // wave col base: 0/64
  const int lr   = lane & 15;
  const int lk   = (lane >> 4) << 3;

  const float* pX[4];
#pragma unroll
  for (int c = 0; c < 4; ++c)
    pX[c] = X + (size_t)(m0 + (c << 5) + rbase) * HID + coff;
  const unsigned short* pB[4];
#pragma unroll
  for (int ni = 0; ni < 4; ++ni)
    pB[ni] = Wb + (size_t)(wnb + (ni << 4) + lr) * HID + lk;

  f4 acc[4][4];
#pragma unroll
  for (int mi = 0; mi < 4; ++mi)
#pragma unroll
    for (int ni = 0; ni < 4; ++ni) acc[mi][ni] = (f4){0.f, 0.f, 0.f, 0.f};

  // A register prefetch: ring of 3 (2 steps ahead); static indices via unroll.
  f4 xa[3][4][2];
#pragma unroll
  for (int c = 0; c < 4; ++c) {
    xa[0][c][0] = *(const f4*)(pX[c]);
    xa[0][c][1] = *(const f4*)(pX[c] + 4);
    xa[1][c][0] = *(const f4*)(pX[c] + 64);
    xa[1][c][1] = *(const f4*)(pX[c] + 68);
  }

#pragma unroll
  for (int ks = 0; ks < 8; ++ks) {
    const int cur = ks % 3;
    short* const Ac = AS + ((ks & 1) << 13);
    // Stage current A tile into LDS (consumes xa[cur] = oldest outstanding
    // loads; deeper prefetch stays in flight through the wait).
#pragma unroll
    for (int c = 0; c < 4; ++c) {
      const int row = (c << 5) + rbase;
      u4 va;
      va[0] = pkbf(xa[cur][c][0][0], xa[cur][c][0][1]);
      va[1] = pkbf(xa[cur][c][0][2], xa[cur][c][0][3]);
      va[2] = pkbf(xa[cur][c][1][0], xa[cur][c][1][1]);
      va[3] = pkbf(xa[cur][c][1][2], xa[cur][c][1][3]);
      *(u4*)&Ac[swz(row, coff)] = va;
    }
    __syncthreads();
    // B fragments for this step (L2-resident W), issued BEFORE the deep xa
    // prefetch so their vmcnt-consume (in-order) doesn't drain the xa loads.
    s8 bg[2][4];
#pragma unroll
    for (int kk = 0; kk < 2; ++kk)
#pragma unroll
      for (int ni = 0; ni < 4; ++ni)
        bg[kk][ni] = *(const s8*)(pB[ni] + (ks << 6) + (kk << 5));
    // Deep prefetch: A tile for step ks+2.
    if (ks < 6) {
      const int k0 = (ks + 2) << 6;
      const int nxt = (ks + 2) % 3;
#pragma unroll
      for (int c = 0; c < 4; ++c) {
        xa[nxt][c][0] = *(const f4*)(pX[c] + k0);
        xa[nxt][c][1] = *(const f4*)(pX[c] + k0 + 4);
      }
    }
#pragma unroll
    for (int kk = 0; kk < 2; ++kk) {
      s8 af[4];
#pragma unroll
      for (int mi = 0; mi < 4; ++mi)
        af[mi] = *(const s8*)&Ac[swz(wmb + (mi << 4) + lr, (kk << 5) + lk)];
#pragma unroll
      for (int mi = 0; mi < 4; ++mi)
#pragma unroll
        for (int ni = 0; ni < 4; ++ni)
          acc[mi][ni] = __builtin_amdgcn_mfma_f32_16x16x32_bf16(af[mi], bg[kk][ni],
                                                                acc[mi][ni], 0, 0, 0);
    }
  }

  // ---- Epilogue: park z tile in LDS (aliases dead staging buffer) ----
  __syncthreads();   // all waves done reading AS
  const int rr = (lane >> 4) << 2;
#pragma unroll
  for (int mi = 0; mi < 4; ++mi)
#pragma unroll
    for (int ni = 0; ni < 4; ++ni)
#pragma unroll
      for (int r = 0; r < 4; ++r)
        ZS[(wmb + (mi << 4) + rr + r) * 128 + wnb + (ni << 4) + lr] = acc[mi][ni][r];
  __syncthreads();

  // (a) stream z tile out
  if (ZB) {
    unsigned short* const Zrow = zbf + (size_t)t0 * 8192 + (bI << 7);
#pragma unroll
    for (int i = 0; i < 16; ++i) {
      const int idx  = (i << 8) + tid;
      const int toff = idx >> 5;
      const int c4   = idx & 31;
      const f4 zv = *(const f4*)&ZS[toff * 128 + (c4 << 2)];
      u2 pk; pk[0] = pkbf(zv[0], zv[1]); pk[1] = pkbf(zv[2], zv[3]);
      *(u2*)(Zrow + (size_t)toff * 8192 + (c4 << 2)) = pk;
    }
  } else {
    float* const Zrow = Out + (size_t)t0 * 8192 + (bI << 7);
#pragma unroll
    for (int i = 0; i < 16; ++i) {
      const int idx  = (i << 8) + tid;
      const int toff = idx >> 5;
      const int c4   = idx & 31;
      *(f4*)(Zrow + (size_t)toff * 8192 + (c4 << 2)) = *(const f4*)&ZS[toff * 128 + (c4 << 2)];
    }
  }
  // (b) fused phase 2a: zero-state scans of the FOUR 32-chunks this block owns
  {
    const float a  = 0.001f * clamp01(tau_mem[0]);
    const float eb = 1.f - 0.001f * clamp01(tau_syn[0]);
    const int col = tid & 127, h = tid >> 7;
    const int chain = (bI << 7) + col;
#pragma unroll
    for (int s = 0; s < 2; ++s) {
      const int r0 = (h << 6) + (s << 5);
      const float* zs = ZS + r0 * 128 + col;   // bank=col&31: 2-way (free)
      float v = 0.f, ii = 0.f;
#pragma unroll 8
      for (int j = 0; j < CHUNK; ++j) {
        const float z = zs[j * 128];
        v  = v + a * (ii - v);
        ii = eb * ii + z;
      }
      const int q = ((blk & 15) << 2) + (h << 1) + s;   // chunk 0..63
      ws[q * CHAINS + chain]                 = v;   // vend
      ws[NCH * CHAINS + q * CHAINS + chain]  = ii;  // iend
    }
  }
}

// ---------------- Phase 2 (fused combine + emit): each thread reconstructs
// its chunk in-state from the end-state prefix (independent loads, closed-form
// M^32), scans 32 steps writing v to Out; q==63 writes finals.
template <int ZB>
__global__ __launch_bounds__(256) void k_emit(const float* __restrict__ tau_syn,
                                              const float* __restrict__ tau_mem,
                                              float* __restrict__ Out,
                                              const unsigned short* __restrict__ zbf,
                                              const float* __restrict__ ws) {
  const int tid = threadIdx.x;
  const int cg = (blockIdx.x & 31) * 64 + (tid & 63);  // f4 chain-group 0..2047
  const int q  = (blockIdx.x >> 5) * 4 + (tid >> 6);   // chunk 0..63 (wave-uniform)
  const float a  = 0.001f * clamp01(tau_mem[0]);
  const float bb = 0.001f * clamp01(tau_syn[0]);
  const float ea = 1.f - a, eb = 1.f - bb;
  // M^32 first row [P,Q]; [M^32]_11 = R
  float P = 1.f, Q = 0.f, R = 1.f;
#pragma unroll
  for (int j = 0; j < CHUNK; ++j) { float Pn = P * ea; Q = P * a + Q * eb; P = Pn; R *= eb; }

  const f4* vend = (const f4*)ws;          // [64][2048]
  const f4* iend = vend + NCH * 2048;
  f4 sv = (f4){0.f, 0.f, 0.f, 0.f}, si = (f4){0.f, 0.f, 0.f, 0.f};
#pragma unroll 4
  for (int p = 0; p < q; ++p) {            // independent, pipelineable loads
    const f4 ve = vend[p * 2048 + cg];
    const f4 ie = iend[p * 2048 + cg];
    const f4 nv = P * sv + Q * si + ve;
    si = R * si + ie;
    sv = nv;
  }

  f4* o4 = (f4*)Out;
  const int tb = q << 5;
  f4 v = sv, ii = si;
#pragma unroll 8
  for (int j = 0; j < CHUNK; ++j) {
    const size_t idx = (size_t)(tb + j) * 2048 + cg;
    f4 z;
    if (ZB) {
      const su4 zb = *(const su4*)(zbf + (((size_t)(tb + j)) << 13) + (cg << 2));
      z[0] = bf2f(zb[0]); z[1] = bf2f(zb[1]); z[2] = bf2f(zb[2]); z[3] = bf2f(zb[3]);
    } else {
      z = o4[idx];
    }
    v  = v + a * (ii - v);
    o4[idx] = v;
    ii = eb * ii + z;
  }
  if (q == NCH - 1) {
    ((f4*)(Out + VOLT))[cg]          = v;    // v_f
    ((f4*)(Out + VOLT + CHAINS))[cg] = ii;   // i_f
  }
}

extern "C" void kernel_launch(void* const* d_in, const int* in_sizes, int n_in,
                              void* d_out, int out_size, void* d_ws, size_t ws_size,
                              hipStream_t stream) {
  const float* X   = (const float*)d_in[0];  // [64][2048][512]
  const float* W   = (const float*)d_in[1];  // [128][512]
  const float* tsy = (const float*)d_in[2];
  const float* tme = (const float*)d_in[3];
  float* Out = (float*)d_out;
  float* ws  = (float*)d_ws;
  unsigned short* Wb  = (unsigned short*)((char*)d_ws + (4u << 20));
  unsigned short* zbf = (unsigned short*)((char*)d_ws + (4u << 20) + (128u << 10));
  const size_t need = (4ull << 20) + (128ull << 10) + (32ull << 20);

  k_wconv<<<32, 256, 0, stream>>>(W, Wb);
  if (ws_size >= need) {
    k_gemm<1><<<1024, 256, 0, stream>>>(X, Wb, Out, zbf, tsy, tme, ws);
    k_emit<1><<<512, 256, 0, stream>>>(tsy, tme, Out, zbf, ws);
  } else {
    k_gemm<0><<<1024, 256, 0, stream>>>(X, Wb, Out, zbf, tsy, tme, ws);
    k_emit<0><<<512, 256, 0, stream>>>(tsy, tme, Out, zbf, ws);
  }
}